// Round 5
// baseline (238.995 us; speedup 1.0000x reference)
//
#include <hip/hip_runtime.h>
#include <stdint.h>

// DBSCAN, N=16384 points in R^3, eps=0.2, minPts=10.
//
// R5 structure (8 launches): move the HEAVY hook rounds off the single CU.
//   k_init   : sq, deg=1, rm=N, counters=0
//   k_edges  : packed-triangular N^2 pass -> edge list + degree counts
//   k_core   : parent[i] = core ? i : BIG  (global)
//   k_hook0  : full-grid over all edges: classify (core-core -> cclist+hook,
//              mixed -> mbuf, else drop). Fire-and-forget global atomicMin
//              hooking: monotone, safe under stale reads (equal observed
//              roots => already connected; survivors re-checked later).
//   k_jump   : full-grid pointer-chase: parent[x] = root(x)
//   k_hook1  : full-grid over cclist: hook root pairs, append still-differing
//              pairs to a small survivor list
//   k_jump   : again
//   k_cc_final: ONE block, parent -> LDS, R4-style contraction rounds over
//              the tiny survivor list to exact convergence, then border
//              root-min (mbuf), scan-order renumber, labels.
//
// Numerics replicate the reference EXACTLY in fp32 (absmax=0 in R1-R4):
//   sq  = (x*x + y*y) + z*z               (left-to-right)
//   dot = fma(z,z', fma(y,y', x*x'))      (BLAS k-ordered FMA chain)
//   d2  = (sq_i + sq_j) - 2.0f*dot ; adj = d2 < 0.04f

#define N_PTS   16384
#define BLOCK   256
#define IPT     2
#define TILE    512
#define NT      (N_PTS / TILE)          // 32
#define NTRI    (NT * (NT + 1) / 2)     // 528 lower-triangle tile pairs
#define EPS2    0.04f
#define MINPTS  10
#define ECAP    262144                  // raw edge list capacity (words)
#define CCAP    262144                  // core-core list capacity
#define MCAP    65536                   // mixed-edge list capacity
#define SCAP    131072                  // survivor list capacity
#define LBUF    1024                    // k_edges per-block LDS staging
#define NCC     1024                    // k_cc_final block size
#define CHUNK   (N_PTS / NCC)           // 16 nodes per thread
#define BIG     N_PTS                   // non-core parent sentinel

__device__ __forceinline__ float dist2(float px, float py, float pz, float sqi, float4 q) {
    float dot = __fmaf_rn(pz, q.z, __fmaf_rn(py, q.y, __fmul_rn(px, q.x)));
    return __fsub_rn(__fadd_rn(sqi, q.w), __fmul_rn(2.0f, dot));
}

__device__ __forceinline__ int pload(const int* p) {
    return __hip_atomic_load(p, __ATOMIC_RELAXED, __HIP_MEMORY_SCOPE_AGENT);
}

// ---------------------------------------------------------------------------
__global__ void k_init(const float* __restrict__ pts, float* __restrict__ sq,
                       int* __restrict__ deg, int* __restrict__ rm,
                       int* __restrict__ cnts) {
    int i = blockIdx.x * BLOCK + threadIdx.x;
    float x = pts[3 * i], y = pts[3 * i + 1], z = pts[3 * i + 2];
    sq[i] = __fadd_rn(__fadd_rn(__fmul_rn(x, x), __fmul_rn(y, y)), __fmul_rn(z, z));
    deg[i] = 1;            // self-neighbor (d=0 < eps)
    rm[i] = BIG;           // border root-min sentinel
    if (i < 8) cnts[i] = 0;   // gcnt, ccnt, mcnt, scnt
}

// Packed triangular N^2: detect eps-pairs (j<i), append packed (i<<14|j),
// count degrees.
__global__ void k_edges(const float* __restrict__ pts, const float* __restrict__ sq,
                        uint32_t* __restrict__ edges, int* __restrict__ gcnt,
                        int* __restrict__ deg) {
    int b = blockIdx.x;
    float t = sqrtf(8.0f * (float)b + 1.0f);
    int bi = (int)((t - 1.0f) * 0.5f);
    while ((bi + 1) * (bi + 2) / 2 <= b) ++bi;
    while (bi * (bi + 1) / 2 > b) --bi;
    int bj = b - bi * (bi + 1) / 2;

    __shared__ float4 sj[TILE];
    __shared__ int sdeg[TILE];
    __shared__ uint32_t lbuf[LBUF];
    __shared__ int lcnt, lbase;
    const int tid = threadIdx.x;
    if (tid == 0) lcnt = 0;
    const int i0 = bi * TILE, j0 = bj * TILE;
    for (int idx = tid; idx < TILE; idx += BLOCK) {
        int j = j0 + idx;
        sj[idx] = make_float4(pts[3 * j], pts[3 * j + 1], pts[3 * j + 2], sq[j]);
        sdeg[idx] = 0;
    }
    __syncthreads();
    float px[IPT], py[IPT], pz[IPT], sqi[IPT];
    int ii[IPT], cnt[IPT];
#pragma unroll
    for (int k = 0; k < IPT; ++k) {
        int i = i0 + k * BLOCK + tid;
        ii[k] = i;
        px[k] = pts[3 * i]; py[k] = pts[3 * i + 1]; pz[k] = pts[3 * i + 2];
        sqi[k] = sq[i]; cnt[k] = 0;
    }
#pragma unroll 4
    for (int j = 0; j < TILE; ++j) {
        float4 q = sj[j];
        int jg = j0 + j;
#pragma unroll
        for (int k = 0; k < IPT; ++k) {
            float d2 = dist2(px[k], py[k], pz[k], sqi[k], q);
            if (d2 < EPS2 && jg < ii[k]) {
                int s = atomicAdd(&lcnt, 1);
                if (s < LBUF) lbuf[s] = ((uint32_t)ii[k] << 14) | (uint32_t)jg;
                ++cnt[k];
                atomicAdd(&sdeg[j], 1);
            }
        }
    }
#pragma unroll
    for (int k = 0; k < IPT; ++k)
        if (cnt[k]) atomicAdd(&deg[ii[k]], cnt[k]);
    __syncthreads();
    for (int idx = tid; idx < TILE; idx += BLOCK)
        if (sdeg[idx]) atomicAdd(&deg[j0 + idx], sdeg[idx]);
    if (tid == 0) {
        int n = min(lcnt, LBUF);
        lcnt = n;
        lbase = atomicAdd(gcnt, n);
    }
    __syncthreads();
    for (int t2 = tid; t2 < lcnt; t2 += BLOCK) {
        int s = lbase + t2;
        if (s < ECAP) edges[s] = lbuf[t2];
    }
}

__global__ void k_core(const int* __restrict__ deg, int* __restrict__ parent) {
    int i = blockIdx.x * BLOCK + threadIdx.x;
    parent[i] = (deg[i] >= MINPTS) ? i : BIG;
}

// Full-grid: classify every raw edge; hook core-core; build cclist + mbuf.
__global__ void k_hook0(const uint32_t* __restrict__ edges, const int* __restrict__ gcnt,
                        int* __restrict__ parent,
                        uint32_t* __restrict__ cclist, int* __restrict__ ccnt,
                        uint32_t* __restrict__ mbuf, int* __restrict__ mcnt) {
    const int n = min(pload(gcnt), ECAP);
    const int lane = threadIdx.x & 63;
    const uint64_t lane_lt = (1ull << lane) - 1;
    for (int e = blockIdx.x * BLOCK + threadIdx.x; e < n; e += gridDim.x * BLOCK) {
        uint32_t p = edges[e];
        int i = (int)(p >> 14), j = (int)(p & (N_PTS - 1));
        bool ci = pload(&parent[i]) < BIG;
        bool cj = pload(&parent[j]) < BIG;
        bool cc = ci && cj;
        bool mx = ci != cj;
        if (cc) atomicMin(&parent[max(i, j)], min(i, j));  // fire-and-forget
        uint64_t m1 = __ballot(cc);
        if (m1) {
            int ldr = (int)__ffsll((unsigned long long)m1) - 1;
            int base = 0;
            if (lane == ldr) base = atomicAdd(ccnt, (int)__popcll(m1));
            base = __shfl(base, ldr);
            if (cc) {
                int pos = base + (int)__popcll(m1 & lane_lt);
                if (pos < CCAP) cclist[pos] = p;
            }
        }
        uint64_t m2 = __ballot(mx);
        if (m2) {
            int ldr = (int)__ffsll((unsigned long long)m2) - 1;
            int base = 0;
            if (lane == ldr) base = atomicAdd(mcnt, (int)__popcll(m2));
            base = __shfl(base, ldr);
            if (mx) {
                // pack (core << 14) | border
                uint32_t pk = ci ? (((uint32_t)i << 14) | (uint32_t)j)
                                 : (((uint32_t)j << 14) | (uint32_t)i);
                int pos = base + (int)__popcll(m2 & lane_lt);
                if (pos < MCAP) mbuf[pos] = pk;
            }
        }
    }
}

// Full-grid pointer-jump: parent[x] = root(x). Only reads + own-entry write.
__global__ void k_jump(int* __restrict__ parent) {
    int x = blockIdx.x * BLOCK + threadIdx.x;
    int p = pload(&parent[x]);
    if (p >= BIG) return;
    int r = p;
    while (true) {
        int q = pload(&parent[r]);
        if (q == r) break;
        r = q;
    }
    if (r != p)
        __hip_atomic_store(&parent[x], r, __ATOMIC_RELAXED, __HIP_MEMORY_SCOPE_AGENT);
}

// Full-grid: hook root pairs of core-core edges; append still-differing pairs.
__global__ void k_hook1(const uint32_t* __restrict__ cclist, const int* __restrict__ ccnt,
                        int* __restrict__ parent,
                        uint32_t* __restrict__ surv, int* __restrict__ scnt) {
    const int n = min(pload(ccnt), CCAP);
    const int lane = threadIdx.x & 63;
    const uint64_t lane_lt = (1ull << lane) - 1;
    for (int e = blockIdx.x * BLOCK + threadIdx.x; e < n; e += gridDim.x * BLOCK) {
        uint32_t p = cclist[e];
        int ri = pload(&parent[(int)(p >> 14)]);
        int rj = pload(&parent[(int)(p & (N_PTS - 1))]);
        bool live = (ri != rj);
        int lo = min(ri, rj), hi = max(ri, rj);
        if (live) atomicMin(&parent[hi], lo);
        uint64_t m = __ballot(live);
        if (m) {
            int ldr = (int)__ffsll((unsigned long long)m) - 1;
            int base = 0;
            if (lane == ldr) base = atomicAdd(scnt, (int)__popcll(m));
            base = __shfl(base, ldr);
            if (live) {
                int pos = base + (int)__popcll(m & lane_lt);
                if (pos < SCAP) surv[pos] = ((uint32_t)hi << 14) | (uint32_t)lo;
            }
        }
    }
}

// ---------------------------------------------------------------------------
__global__ void __launch_bounds__(NCC)
k_cc_final(const int* __restrict__ parent_g,
           const uint32_t* __restrict__ surv, const int* __restrict__ scnt,
           const int* __restrict__ mcnt, const uint32_t* __restrict__ mbuf,
           int* __restrict__ rm, uint32_t* __restrict__ bufA, uint32_t* __restrict__ bufB,
           int* __restrict__ rank, float* __restrict__ out) {
    __shared__ int parent[N_PTS];                    // 64 KB
    __shared__ int s_nout;
    __shared__ int wsum[16];
    const int tid = threadIdx.x;
    const int lane = tid & 63;
    const uint64_t lane_lt = (1ull << lane) - 1;

    // load parent snapshot (coalesced)
#pragma unroll
    for (int k = 0; k < CHUNK; ++k) {
        int x = k * NCC + tid;
        parent[x] = parent_g[x];
    }
    __syncthreads();

    int n_in = min(pload(scnt), SCAP);
    const uint32_t* cur = surv;

    // contraction rounds over the (small) survivor list
    for (int r = 0; r < 24; ++r) {
        uint32_t* nxt = (r & 1) ? bufB : bufA;
        if (tid == 0) s_nout = 0;
        __syncthreads();
        const int n4 = (n_in + 3) & ~3;
        for (int bb = tid * 4; bb < n4; bb += NCC * 4) {
            uint4 pk = *(const uint4*)(cur + bb);
#pragma unroll
            for (int k = 0; k < 4; ++k) {
                uint32_t p = (k == 0) ? pk.x : (k == 1) ? pk.y : (k == 2) ? pk.z : pk.w;
                bool valid = (bb + k) < n_in;
                int ri = 0, rj = 0;
                if (valid) {
                    ri = parent[(int)(p >> 14)];
                    rj = parent[(int)(p & (N_PTS - 1))];
                }
                bool live = valid && (ri != rj);
                int lo = min(ri, rj), hi = max(ri, rj);
                if (live) atomicMin(&parent[hi], lo);     // LDS, fire-and-forget
                uint64_t m = __ballot(live);
                if (m) {
                    int ldr = (int)__ffsll((unsigned long long)m) - 1;
                    int base = 0;
                    if (lane == ldr) base = atomicAdd(&s_nout, (int)__popcll(m));
                    base = __shfl(base, ldr);
                    if (live) {
                        int pos = base + (int)__popcll(m & lane_lt);
                        if (pos < SCAP) nxt[pos] = ((uint32_t)hi << 14) | (uint32_t)lo;
                    }
                }
            }
        }
        __syncthreads();
        // compress: wavefront chase, 16 independent streams per thread
        int v[CHUNK];
#pragma unroll
        for (int k = 0; k < CHUNK; ++k) v[k] = parent[k * NCC + tid];
        bool any = true;
        while (any) {
            any = false;
#pragma unroll
            for (int k = 0; k < CHUNK; ++k) {
                if (v[k] < BIG) {
                    int q = parent[v[k]];
                    if (q != v[k]) { v[k] = q; any = true; }
                }
            }
        }
#pragma unroll
        for (int k = 0; k < CHUNK; ++k)
            if (v[k] < BIG) parent[k * NCC + tid] = v[k];
        __syncthreads();
        int nout = s_nout;
        if (nout == 0) break;                        // uniform
        n_in = min(nout, SCAP);
        cur = nxt;
    }

    // border root-min over mixed edges (global fire-and-forget)
    int nm = min(pload(mcnt), MCAP);
    for (int e = tid; e < nm; e += NCC) {
        uint32_t p = mbuf[e];
        int c = (int)(p >> 14), b = (int)(p & (N_PTS - 1));
        atomicMin(&rm[b], parent[c]);                // parent[c] = final root
    }

    // rank = exclusive count of roots before each root index
    const int base_node = tid * CHUNK;
    int fl[CHUNK];
    int s = 0;
#pragma unroll
    for (int k = 0; k < CHUNK; ++k) {
        fl[k] = (parent[base_node + k] == base_node + k) ? 1 : 0;
        s += fl[k];
    }
    int wv = tid >> 6;                               // 16 waves
    int incl = s;
#pragma unroll
    for (int d = 1; d < 64; d <<= 1) {
        int t = __shfl_up(incl, d, 64);
        if (lane >= d) incl += t;
    }
    if (lane == 63) wsum[wv] = incl;
    __syncthreads();                                 // drains phase-C atomics too
    int wbase = 0;
    for (int w = 0; w < wv; ++w) wbase += wsum[w];
    int c = wbase + incl - s;
#pragma unroll
    for (int k = 0; k < CHUNK; ++k)
        if (fl[k]) rank[base_node + k] = c++;
    __syncthreads();

    // labels
#pragma unroll
    for (int k = 0; k < CHUNK; ++k) {
        int x = k * NCC + tid;                       // coalesced writes
        int p0 = parent[x];
        if (p0 < BIG) {
            out[x] = (float)rank[p0];
        } else {
            int rv = pload(&rm[x]);
            out[x] = (rv < BIG) ? (float)rank[rv] : -1.0f;
        }
    }
}

extern "C" void kernel_launch(void* const* d_in, const int* in_sizes, int n_in,
                              void* d_out, int out_size, void* d_ws, size_t ws_size,
                              hipStream_t stream) {
    (void)in_sizes; (void)n_in; (void)out_size; (void)ws_size;
    const float* pts = (const float*)d_in[0];
    float* out = (float*)d_out;

    int* ibase = (int*)d_ws;
    float*    sq     = (float*)d_ws;                 // N
    int*      deg    = ibase + 1 * N_PTS;            // N
    int*      rm     = ibase + 2 * N_PTS;            // N
    int*      parent = ibase + 3 * N_PTS;            // N
    int*      rank   = ibase + 4 * N_PTS;            // N
    int*      cnts   = ibase + 5 * N_PTS;            // 64 words
    int*      gcnt = cnts + 0, *ccnt = cnts + 1, *mcnt = cnts + 2, *scnt = cnts + 3;
    uint32_t* edges  = (uint32_t*)(ibase + 5 * N_PTS + 64);
    uint32_t* cclist = edges  + ECAP + 16;
    uint32_t* mbuf   = cclist + CCAP + 16;
    uint32_t* surv   = mbuf   + MCAP + 16;
    uint32_t* bufA   = surv   + SCAP + 16;
    uint32_t* bufB   = bufA   + SCAP + 16;           // total ~3.6 MB

    dim3 blk(BLOCK);
    dim3 gN(N_PTS / BLOCK);                          // 64
    k_init <<<gN, blk, 0, stream>>>(pts, sq, deg, rm, cnts);
    k_edges<<<dim3(NTRI), blk, 0, stream>>>(pts, sq, edges, gcnt, deg);
    k_core <<<gN, blk, 0, stream>>>(deg, parent);
    k_hook0<<<dim3(256), blk, 0, stream>>>(edges, gcnt, parent, cclist, ccnt, mbuf, mcnt);
    k_jump <<<gN, blk, 0, stream>>>(parent);
    k_hook1<<<dim3(256), blk, 0, stream>>>(cclist, ccnt, parent, surv, scnt);
    k_jump <<<gN, blk, 0, stream>>>(parent);
    k_cc_final<<<dim3(1), dim3(NCC), 0, stream>>>(parent, surv, scnt, mcnt, mbuf,
                                                  rm, bufA, bufB, rank, out);
}

// Round 6
// 229.541 us; speedup vs baseline: 1.0412x; 1.0412x over previous
//
#include <hip/hip_runtime.h>
#include <stdint.h>

// DBSCAN, N=16384 points in R^3, eps=0.2, minPts=10.
//
// R6 (7 launches): R5 tail kept; k_edges re-tiled for occupancy.
//   k_init   : sq, deg=1, rm=N, parent=i, counters=0
//   k_edges  : packed-triangular N^2 pass, i-tile 512 x j-tile 128 ->
//              2112 blocks (8.25 waves/SIMD; R5's 528 blocks = 2.06 waves/SIMD
//              left VALUBusy at 40%). Edge list + degree counts.
//   k_hook0  : full-grid over all edges: classify via deg (core-core ->
//              cclist + fire-and-forget global atomicMin hook, mixed -> mbuf)
//   k_jump   : parent[x] = root(x)
//   k_hook1  : hook root pairs of cclist, append still-differing survivors
//   k_jump   : again
//   k_cc_final: ONE block, parent -> LDS, contraction rounds on the small
//              survivor list, border root-min, scan-order renumber, labels.
//
// Numerics replicate the reference EXACTLY in fp32 (absmax=0 in R1-R5):
//   sq  = (x*x + y*y) + z*z               (left-to-right)
//   dot = fma(z,z', fma(y,y', x*x'))      (BLAS k-ordered FMA chain)
//   d2  = (sq_i + sq_j) - 2.0f*dot ; adj = d2 < 0.04f

#define N_PTS   16384
#define BLOCK   256
#define IPT     2
#define ITILE   512                     // i-tile (IPT * BLOCK)
#define JT      128                     // j-tile
#define NTI     (N_PTS / ITILE)         // 32 i-tiles
#define NBLK    (2 * NTI * (NTI + 1))   // 2112 triangular blocks
#define EPS2    0.04f
#define MINPTS  10
#define ECAP    262144                  // raw edge list capacity (words)
#define CCAP    262144                  // core-core list capacity
#define MCAP    65536                   // mixed-edge list capacity
#define SCAP    131072                  // survivor list capacity
#define LBUF    1024                    // k_edges per-block LDS staging
#define NCC     1024                    // k_cc_final block size
#define CHUNK   (N_PTS / NCC)           // 16 nodes per thread
#define BIG     N_PTS

__device__ __forceinline__ float dist2(float px, float py, float pz, float sqi, float4 q) {
    float dot = __fmaf_rn(pz, q.z, __fmaf_rn(py, q.y, __fmul_rn(px, q.x)));
    return __fsub_rn(__fadd_rn(sqi, q.w), __fmul_rn(2.0f, dot));
}

__device__ __forceinline__ int pload(const int* p) {
    return __hip_atomic_load(p, __ATOMIC_RELAXED, __HIP_MEMORY_SCOPE_AGENT);
}

// ---------------------------------------------------------------------------
__global__ void k_init(const float* __restrict__ pts, float* __restrict__ sq,
                       int* __restrict__ deg, int* __restrict__ rm,
                       int* __restrict__ parent, int* __restrict__ cnts) {
    int i = blockIdx.x * BLOCK + threadIdx.x;
    float x = pts[3 * i], y = pts[3 * i + 1], z = pts[3 * i + 2];
    sq[i] = __fadd_rn(__fadd_rn(__fmul_rn(x, x), __fmul_rn(y, y)), __fmul_rn(z, z));
    deg[i] = 1;            // self-neighbor (d=0 < eps)
    rm[i] = BIG;           // border root-min sentinel
    parent[i] = i;         // hooks only ever target core nodes (deg-guarded)
    if (i < 8) cnts[i] = 0;   // gcnt, ccnt, mcnt, scnt
}

// Packed triangular N^2: i-tile 512, j-tile 128. Detect eps-pairs (j<i),
// append packed (i<<14|j), count degrees.
__global__ void k_edges(const float* __restrict__ pts, const float* __restrict__ sq,
                        uint32_t* __restrict__ edges, int* __restrict__ gcnt,
                        int* __restrict__ deg) {
    // decode b -> (bi, jc): cumulative blocks before i-tile bi = 2*bi*(bi+1)
    int b = blockIdx.x;
    float t = sqrtf(2.0f * (float)b + 1.0f);
    int bi = (int)((t - 1.0f) * 0.5f);
    while (2 * (bi + 1) * (bi + 2) <= b) ++bi;   // fp round-off fixups
    while (2 * bi * (bi + 1) > b) --bi;
    int jc = b - 2 * bi * (bi + 1);              // 0 .. 4*(bi+1)-1
    const int i0 = bi * ITILE, j0 = jc * JT;

    __shared__ float4 sj[JT];
    __shared__ int sdeg[JT];
    __shared__ uint32_t lbuf[LBUF];
    __shared__ int lcnt, lbase;
    const int tid = threadIdx.x;
    if (tid == 0) lcnt = 0;
    if (tid < JT) {
        int j = j0 + tid;
        sj[tid] = make_float4(pts[3 * j], pts[3 * j + 1], pts[3 * j + 2], sq[j]);
        sdeg[tid] = 0;
    }
    __syncthreads();
    float px[IPT], py[IPT], pz[IPT], sqi[IPT];
    int ii[IPT], cnt[IPT];
#pragma unroll
    for (int k = 0; k < IPT; ++k) {
        int i = i0 + k * BLOCK + tid;
        ii[k] = i;
        px[k] = pts[3 * i]; py[k] = pts[3 * i + 1]; pz[k] = pts[3 * i + 2];
        sqi[k] = sq[i]; cnt[k] = 0;
    }
#pragma unroll 4
    for (int j = 0; j < JT; ++j) {
        float4 q = sj[j];
        int jg = j0 + j;
#pragma unroll
        for (int k = 0; k < IPT; ++k) {
            float d2 = dist2(px[k], py[k], pz[k], sqi[k], q);
            if (d2 < EPS2 && jg < ii[k]) {       // each unordered pair once
                int s = atomicAdd(&lcnt, 1);
                if (s < LBUF) lbuf[s] = ((uint32_t)ii[k] << 14) | (uint32_t)jg;
                ++cnt[k];
                atomicAdd(&sdeg[j], 1);
            }
        }
    }
#pragma unroll
    for (int k = 0; k < IPT; ++k)
        if (cnt[k]) atomicAdd(&deg[ii[k]], cnt[k]);
    __syncthreads();
    if (tid < JT && sdeg[tid]) atomicAdd(&deg[j0 + tid], sdeg[tid]);
    if (tid == 0) {
        int n = min(lcnt, LBUF);
        lcnt = n;
        lbase = atomicAdd(gcnt, n);              // one global atomic per block
    }
    __syncthreads();
    for (int t2 = tid; t2 < lcnt; t2 += BLOCK) {
        int s = lbase + t2;
        if (s < ECAP) edges[s] = lbuf[t2];
    }
}

// Full-grid: classify every raw edge via deg; hook core-core; build cclist+mbuf.
__global__ void k_hook0(const uint32_t* __restrict__ edges, const int* __restrict__ gcnt,
                        const int* __restrict__ deg, int* __restrict__ parent,
                        uint32_t* __restrict__ cclist, int* __restrict__ ccnt,
                        uint32_t* __restrict__ mbuf, int* __restrict__ mcnt) {
    const int n = min(pload(gcnt), ECAP);
    const int lane = threadIdx.x & 63;
    const uint64_t lane_lt = (1ull << lane) - 1;
    for (int e = blockIdx.x * BLOCK + threadIdx.x; e < n; e += gridDim.x * BLOCK) {
        uint32_t p = edges[e];
        int i = (int)(p >> 14), j = (int)(p & (N_PTS - 1));
        bool ci = deg[i] >= MINPTS;
        bool cj = deg[j] >= MINPTS;
        bool cc = ci && cj;
        bool mx = ci != cj;
        if (cc) atomicMin(&parent[max(i, j)], min(i, j));  // fire-and-forget
        uint64_t m1 = __ballot(cc);
        if (m1) {
            int ldr = (int)__ffsll((unsigned long long)m1) - 1;
            int base = 0;
            if (lane == ldr) base = atomicAdd(ccnt, (int)__popcll(m1));
            base = __shfl(base, ldr);
            if (cc) {
                int pos = base + (int)__popcll(m1 & lane_lt);
                if (pos < CCAP) cclist[pos] = p;
            }
        }
        uint64_t m2 = __ballot(mx);
        if (m2) {
            int ldr = (int)__ffsll((unsigned long long)m2) - 1;
            int base = 0;
            if (lane == ldr) base = atomicAdd(mcnt, (int)__popcll(m2));
            base = __shfl(base, ldr);
            if (mx) {
                uint32_t pk = ci ? (((uint32_t)i << 14) | (uint32_t)j)
                                 : (((uint32_t)j << 14) | (uint32_t)i);  // core<<14|border
                int pos = base + (int)__popcll(m2 & lane_lt);
                if (pos < MCAP) mbuf[pos] = pk;
            }
        }
    }
}

// Full-grid pointer-jump: parent[x] = root(x).
__global__ void k_jump(int* __restrict__ parent) {
    int x = blockIdx.x * BLOCK + threadIdx.x;
    int p = pload(&parent[x]);
    if (p == x) return;
    int r = p;
    while (true) {
        int q = pload(&parent[r]);
        if (q == r) break;
        r = q;
    }
    if (r != p)
        __hip_atomic_store(&parent[x], r, __ATOMIC_RELAXED, __HIP_MEMORY_SCOPE_AGENT);
}

// Full-grid: hook root pairs of core-core edges; append still-differing pairs.
__global__ void k_hook1(const uint32_t* __restrict__ cclist, const int* __restrict__ ccnt,
                        int* __restrict__ parent,
                        uint32_t* __restrict__ surv, int* __restrict__ scnt) {
    const int n = min(pload(ccnt), CCAP);
    const int lane = threadIdx.x & 63;
    const uint64_t lane_lt = (1ull << lane) - 1;
    for (int e = blockIdx.x * BLOCK + threadIdx.x; e < n; e += gridDim.x * BLOCK) {
        uint32_t p = cclist[e];
        int ri = pload(&parent[(int)(p >> 14)]);
        int rj = pload(&parent[(int)(p & (N_PTS - 1))]);
        bool live = (ri != rj);
        int lo = min(ri, rj), hi = max(ri, rj);
        if (live) atomicMin(&parent[hi], lo);
        uint64_t m = __ballot(live);
        if (m) {
            int ldr = (int)__ffsll((unsigned long long)m) - 1;
            int base = 0;
            if (lane == ldr) base = atomicAdd(scnt, (int)__popcll(m));
            base = __shfl(base, ldr);
            if (live) {
                int pos = base + (int)__popcll(m & lane_lt);
                if (pos < SCAP) surv[pos] = ((uint32_t)hi << 14) | (uint32_t)lo;
            }
        }
    }
}

// ---------------------------------------------------------------------------
__global__ void __launch_bounds__(NCC)
k_cc_final(const int* __restrict__ parent_g, const int* __restrict__ deg,
           const uint32_t* __restrict__ surv, const int* __restrict__ scnt,
           const int* __restrict__ mcnt, const uint32_t* __restrict__ mbuf,
           int* __restrict__ rm, uint32_t* __restrict__ bufA, uint32_t* __restrict__ bufB,
           int* __restrict__ rank, float* __restrict__ out) {
    __shared__ int parent[N_PTS];                    // 64 KB
    __shared__ int s_nout;
    __shared__ int wsum[16];
    const int tid = threadIdx.x;
    const int lane = tid & 63;
    const uint64_t lane_lt = (1ull << lane) - 1;

#pragma unroll
    for (int k = 0; k < CHUNK; ++k) {
        int x = k * NCC + tid;
        parent[x] = parent_g[x];
    }
    __syncthreads();

    int n_in = min(pload(scnt), SCAP);
    const uint32_t* cur = surv;

    // contraction rounds over the (small) survivor list
    for (int r = 0; r < 24; ++r) {
        uint32_t* nxt = (r & 1) ? bufB : bufA;
        if (tid == 0) s_nout = 0;
        __syncthreads();
        const int n4 = (n_in + 3) & ~3;
        for (int bb = tid * 4; bb < n4; bb += NCC * 4) {
            uint4 pk = *(const uint4*)(cur + bb);
#pragma unroll
            for (int k = 0; k < 4; ++k) {
                uint32_t p = (k == 0) ? pk.x : (k == 1) ? pk.y : (k == 2) ? pk.z : pk.w;
                bool valid = (bb + k) < n_in;
                int ri = 0, rj = 0;
                if (valid) {
                    ri = parent[(int)(p >> 14)];
                    rj = parent[(int)(p & (N_PTS - 1))];
                }
                bool live = valid && (ri != rj);
                int lo = min(ri, rj), hi = max(ri, rj);
                if (live) atomicMin(&parent[hi], lo);     // LDS fire-and-forget
                uint64_t m = __ballot(live);
                if (m) {
                    int ldr = (int)__ffsll((unsigned long long)m) - 1;
                    int base = 0;
                    if (lane == ldr) base = atomicAdd(&s_nout, (int)__popcll(m));
                    base = __shfl(base, ldr);
                    if (live) {
                        int pos = base + (int)__popcll(m & lane_lt);
                        if (pos < SCAP) nxt[pos] = ((uint32_t)hi << 14) | (uint32_t)lo;
                    }
                }
            }
        }
        __syncthreads();
        // compress: wavefront chase, 16 independent streams per thread
        int v[CHUNK];
#pragma unroll
        for (int k = 0; k < CHUNK; ++k) v[k] = parent[k * NCC + tid];
        bool any = true;
        while (any) {
            any = false;
#pragma unroll
            for (int k = 0; k < CHUNK; ++k) {
                int q = parent[v[k]];
                if (q != v[k]) { v[k] = q; any = true; }
            }
        }
#pragma unroll
        for (int k = 0; k < CHUNK; ++k) parent[k * NCC + tid] = v[k];
        __syncthreads();
        int nout = s_nout;
        if (nout == 0) break;                        // uniform
        n_in = min(nout, SCAP);
        cur = nxt;
    }

    // border root-min over mixed edges (global fire-and-forget)
    int nm = min(pload(mcnt), MCAP);
    for (int e = tid; e < nm; e += NCC) {
        uint32_t p = mbuf[e];
        int c = (int)(p >> 14), b = (int)(p & (N_PTS - 1));
        atomicMin(&rm[b], parent[c]);                // parent[c] = final root
    }

    // rank = exclusive count of roots before each root index (core roots only)
    const int base_node = tid * CHUNK;
    int fl[CHUNK];
    int s = 0;
#pragma unroll
    for (int k = 0; k < CHUNK; ++k) {
        int x = base_node + k;
        fl[k] = (parent[x] == x && deg[x] >= MINPTS) ? 1 : 0;
        s += fl[k];
    }
    int wv = tid >> 6;                               // 16 waves
    int incl = s;
#pragma unroll
    for (int d = 1; d < 64; d <<= 1) {
        int t = __shfl_up(incl, d, 64);
        if (lane >= d) incl += t;
    }
    if (lane == 63) wsum[wv] = incl;
    __syncthreads();
    int wbase = 0;
    for (int w = 0; w < wv; ++w) wbase += wsum[w];
    int c = wbase + incl - s;
#pragma unroll
    for (int k = 0; k < CHUNK; ++k)
        if (fl[k]) rank[base_node + k] = c++;
    __syncthreads();

    // labels
#pragma unroll
    for (int k = 0; k < CHUNK; ++k) {
        int x = k * NCC + tid;                       // coalesced
        if (deg[x] >= MINPTS) {
            out[x] = (float)rank[parent[x]];
        } else {
            int rv = pload(&rm[x]);
            out[x] = (rv < BIG) ? (float)rank[rv] : -1.0f;
        }
    }
}

extern "C" void kernel_launch(void* const* d_in, const int* in_sizes, int n_in,
                              void* d_out, int out_size, void* d_ws, size_t ws_size,
                              hipStream_t stream) {
    (void)in_sizes; (void)n_in; (void)out_size; (void)ws_size;
    const float* pts = (const float*)d_in[0];
    float* out = (float*)d_out;

    int* ibase = (int*)d_ws;
    float*    sq     = (float*)d_ws;                 // N
    int*      deg    = ibase + 1 * N_PTS;            // N
    int*      rm     = ibase + 2 * N_PTS;            // N
    int*      parent = ibase + 3 * N_PTS;            // N
    int*      rank   = ibase + 4 * N_PTS;            // N
    int*      cnts   = ibase + 5 * N_PTS;            // 64 words
    int*      gcnt = cnts + 0, *ccnt = cnts + 1, *mcnt = cnts + 2, *scnt = cnts + 3;
    uint32_t* edges  = (uint32_t*)(ibase + 5 * N_PTS + 64);
    uint32_t* cclist = edges  + ECAP + 16;
    uint32_t* mbuf   = cclist + CCAP + 16;
    uint32_t* surv   = mbuf   + MCAP + 16;
    uint32_t* bufA   = surv   + SCAP + 16;
    uint32_t* bufB   = bufA   + SCAP + 16;           // total ~3.6 MB

    dim3 blk(BLOCK);
    dim3 gN(N_PTS / BLOCK);                          // 64
    k_init <<<gN, blk, 0, stream>>>(pts, sq, deg, rm, parent, cnts);
    k_edges<<<dim3(NBLK), blk, 0, stream>>>(pts, sq, edges, gcnt, deg);
    k_hook0<<<dim3(256), blk, 0, stream>>>(edges, gcnt, deg, parent, cclist, ccnt, mbuf, mcnt);
    k_jump <<<gN, blk, 0, stream>>>(parent);
    k_hook1<<<dim3(256), blk, 0, stream>>>(cclist, ccnt, parent, surv, scnt);
    k_jump <<<gN, blk, 0, stream>>>(parent);
    k_cc_final<<<dim3(1), dim3(NCC), 0, stream>>>(parent, deg, surv, scnt, mcnt, mbuf,
                                                  rm, bufA, bufB, rank, out);
}

// Round 7
// 211.074 us; speedup vs baseline: 1.1323x; 1.0875x over previous
//
#include <hip/hip_runtime.h>
#include <stdint.h>

// DBSCAN, N=16384 points in R^3, eps=0.2, minPts=10.
//
// R7 (6 launches):
//   k_init   : deg=1, rm=N, parent=i, counters=0
//   k_edges  : packed-triangular N^2, i-tile 1024 (IPT=4) x j-tile 128,
//              1088 blocks. Diagonal blocks (128) take a slow path with the
//              jg<i test; the 960 off-diagonal blocks skip it (R6 was
//              instruction-count-bound: ~16 instr/pair -> target ~9).
//              sq computed in-register (same intrinsic sequence, bit-identical).
//   k_hook0  : full-grid classify (deg): core-core -> cclist + global
//              atomicMin hook; mixed -> mbuf
//   k_jump   : parent[x] = root(x)
//   k_hook1  : hook root pairs of cclist, append still-differing survivors
//   k_cc_final: ONE block: parent -> LDS, initial compress (replaces the old
//              2nd k_jump), contraction rounds on the small survivor list,
//              border root-min, scan-order renumber, labels.
//
// Numerics replicate the reference EXACTLY in fp32 (absmax=0 in R1-R6):
//   sq  = (x*x + y*y) + z*z               (left-to-right)
//   dot = fma(z,z', fma(y,y', x*x'))      (BLAS k-ordered FMA chain)
//   d2  = (sq_i + sq_j) - 2.0f*dot ; adj = d2 < 0.04f

#define N_PTS   16384
#define BLOCK   256
#define IPT     4
#define ITILE   1024                    // IPT * BLOCK
#define JT      128
#define NTI     (N_PTS / ITILE)         // 16
#define NBLK    (4 * NTI * (NTI + 1))   // 1088 triangular blocks
#define EPS2    0.04f
#define MINPTS  10
#define ECAP    262144
#define CCAP    262144
#define MCAP    65536
#define SCAP    131072
#define LBUF    1024
#define NCC     1024
#define CHUNK   (N_PTS / NCC)           // 16
#define BIG     N_PTS

__device__ __forceinline__ float dist2(float px, float py, float pz, float sqi, float4 q) {
    float dot = __fmaf_rn(pz, q.z, __fmaf_rn(py, q.y, __fmul_rn(px, q.x)));
    return __fsub_rn(__fadd_rn(sqi, q.w), __fmul_rn(2.0f, dot));
}

__device__ __forceinline__ float sqsum(float x, float y, float z) {
    return __fadd_rn(__fadd_rn(__fmul_rn(x, x), __fmul_rn(y, y)), __fmul_rn(z, z));
}

__device__ __forceinline__ int pload(const int* p) {
    return __hip_atomic_load(p, __ATOMIC_RELAXED, __HIP_MEMORY_SCOPE_AGENT);
}

// ---------------------------------------------------------------------------
__global__ void k_init(int* __restrict__ deg, int* __restrict__ rm,
                       int* __restrict__ parent, int* __restrict__ cnts) {
    int i = blockIdx.x * BLOCK + threadIdx.x;
    deg[i] = 1;            // self-neighbor (d=0 < eps)
    rm[i] = BIG;           // border root-min sentinel
    parent[i] = i;
    if (i < 8) cnts[i] = 0;
}

// Packed triangular N^2: i-tile 1024, j-tile 128.
__global__ void k_edges(const float* __restrict__ pts,
                        uint32_t* __restrict__ edges, int* __restrict__ gcnt,
                        int* __restrict__ deg) {
    // cumulative blocks before i-tile bi = 4*bi*(bi+1); solve for bi
    int b = blockIdx.x;
    float t = sqrtf((float)b + 1.0f);
    int bi = (int)((t - 1.0f) * 0.5f);
    while (4 * (bi + 1) * (bi + 2) <= b) ++bi;   // fp round-off fixups
    while (4 * bi * (bi + 1) > b) --bi;
    int jc = b - 4 * bi * (bi + 1);              // 0 .. 8*(bi+1)-1
    const int i0 = bi * ITILE, j0 = jc * JT;
    const bool diag = (jc >= 8 * bi);            // j-chunk overlaps i-range

    __shared__ float4 sj[JT];
    __shared__ int sdeg[JT];
    __shared__ uint32_t lbuf[LBUF];
    __shared__ int lcnt, lbase;
    const int tid = threadIdx.x;
    if (tid == 0) lcnt = 0;
    if (tid < JT) {
        int j = j0 + tid;
        float x = pts[3 * j], y = pts[3 * j + 1], z = pts[3 * j + 2];
        sj[tid] = make_float4(x, y, z, sqsum(x, y, z));
        sdeg[tid] = 0;
    }
    __syncthreads();
    float px[IPT], py[IPT], pz[IPT], sqi[IPT];
    int ii[IPT], cnt[IPT];
#pragma unroll
    for (int k = 0; k < IPT; ++k) {
        int i = i0 + k * BLOCK + tid;
        ii[k] = i;
        px[k] = pts[3 * i]; py[k] = pts[3 * i + 1]; pz[k] = pts[3 * i + 2];
        sqi[k] = sqsum(px[k], py[k], pz[k]);
        cnt[k] = 0;
    }
    if (!diag) {
        // fast path: every j here has jg < ii[k] automatically
#pragma unroll 4
        for (int j = 0; j < JT; ++j) {
            float4 q = sj[j];
            int jg = j0 + j;
#pragma unroll
            for (int k = 0; k < IPT; ++k) {
                float d2 = dist2(px[k], py[k], pz[k], sqi[k], q);
                if (d2 < EPS2) {
                    int s = atomicAdd(&lcnt, 1);
                    if (s < LBUF) lbuf[s] = ((uint32_t)ii[k] << 14) | (uint32_t)jg;
                    ++cnt[k];
                    atomicAdd(&sdeg[j], 1);
                }
            }
        }
    } else {
#pragma unroll 4
        for (int j = 0; j < JT; ++j) {
            float4 q = sj[j];
            int jg = j0 + j;
#pragma unroll
            for (int k = 0; k < IPT; ++k) {
                float d2 = dist2(px[k], py[k], pz[k], sqi[k], q);
                if (d2 < EPS2 && jg < ii[k]) {
                    int s = atomicAdd(&lcnt, 1);
                    if (s < LBUF) lbuf[s] = ((uint32_t)ii[k] << 14) | (uint32_t)jg;
                    ++cnt[k];
                    atomicAdd(&sdeg[j], 1);
                }
            }
        }
    }
#pragma unroll
    for (int k = 0; k < IPT; ++k)
        if (cnt[k]) atomicAdd(&deg[ii[k]], cnt[k]);
    __syncthreads();
    if (tid < JT && sdeg[tid]) atomicAdd(&deg[j0 + tid], sdeg[tid]);
    if (tid == 0) {
        int n = min(lcnt, LBUF);
        lcnt = n;
        lbase = atomicAdd(gcnt, n);              // one global atomic per block
    }
    __syncthreads();
    for (int t2 = tid; t2 < lcnt; t2 += BLOCK) {
        int s = lbase + t2;
        if (s < ECAP) edges[s] = lbuf[t2];
    }
}

// Full-grid: classify every raw edge via deg; hook core-core; build cclist+mbuf.
__global__ void k_hook0(const uint32_t* __restrict__ edges, const int* __restrict__ gcnt,
                        const int* __restrict__ deg, int* __restrict__ parent,
                        uint32_t* __restrict__ cclist, int* __restrict__ ccnt,
                        uint32_t* __restrict__ mbuf, int* __restrict__ mcnt) {
    const int n = min(pload(gcnt), ECAP);
    const int lane = threadIdx.x & 63;
    const uint64_t lane_lt = (1ull << lane) - 1;
    for (int e = blockIdx.x * BLOCK + threadIdx.x; e < n; e += gridDim.x * BLOCK) {
        uint32_t p = edges[e];
        int i = (int)(p >> 14), j = (int)(p & (N_PTS - 1));
        bool ci = deg[i] >= MINPTS;
        bool cj = deg[j] >= MINPTS;
        bool cc = ci && cj;
        bool mx = ci != cj;
        if (cc) atomicMin(&parent[max(i, j)], min(i, j));  // fire-and-forget
        uint64_t m1 = __ballot(cc);
        if (m1) {
            int ldr = (int)__ffsll((unsigned long long)m1) - 1;
            int base = 0;
            if (lane == ldr) base = atomicAdd(ccnt, (int)__popcll(m1));
            base = __shfl(base, ldr);
            if (cc) {
                int pos = base + (int)__popcll(m1 & lane_lt);
                if (pos < CCAP) cclist[pos] = p;
            }
        }
        uint64_t m2 = __ballot(mx);
        if (m2) {
            int ldr = (int)__ffsll((unsigned long long)m2) - 1;
            int base = 0;
            if (lane == ldr) base = atomicAdd(mcnt, (int)__popcll(m2));
            base = __shfl(base, ldr);
            if (mx) {
                uint32_t pk = ci ? (((uint32_t)i << 14) | (uint32_t)j)
                                 : (((uint32_t)j << 14) | (uint32_t)i);  // core<<14|border
                int pos = base + (int)__popcll(m2 & lane_lt);
                if (pos < MCAP) mbuf[pos] = pk;
            }
        }
    }
}

// Full-grid pointer-jump: parent[x] = root(x).
__global__ void k_jump(int* __restrict__ parent) {
    int x = blockIdx.x * BLOCK + threadIdx.x;
    int p = pload(&parent[x]);
    if (p == x) return;
    int r = p;
    while (true) {
        int q = pload(&parent[r]);
        if (q == r) break;
        r = q;
    }
    if (r != p)
        __hip_atomic_store(&parent[x], r, __ATOMIC_RELAXED, __HIP_MEMORY_SCOPE_AGENT);
}

// Full-grid: hook root pairs of core-core edges; append still-differing pairs.
__global__ void k_hook1(const uint32_t* __restrict__ cclist, const int* __restrict__ ccnt,
                        int* __restrict__ parent,
                        uint32_t* __restrict__ surv, int* __restrict__ scnt) {
    const int n = min(pload(ccnt), CCAP);
    const int lane = threadIdx.x & 63;
    const uint64_t lane_lt = (1ull << lane) - 1;
    for (int e = blockIdx.x * BLOCK + threadIdx.x; e < n; e += gridDim.x * BLOCK) {
        uint32_t p = cclist[e];
        int ri = pload(&parent[(int)(p >> 14)]);
        int rj = pload(&parent[(int)(p & (N_PTS - 1))]);
        bool live = (ri != rj);
        int lo = min(ri, rj), hi = max(ri, rj);
        if (live) atomicMin(&parent[hi], lo);
        uint64_t m = __ballot(live);
        if (m) {
            int ldr = (int)__ffsll((unsigned long long)m) - 1;
            int base = 0;
            if (lane == ldr) base = atomicAdd(scnt, (int)__popcll(m));
            base = __shfl(base, ldr);
            if (live) {
                int pos = base + (int)__popcll(m & lane_lt);
                if (pos < SCAP) surv[pos] = ((uint32_t)hi << 14) | (uint32_t)lo;
            }
        }
    }
}

// ---------------------------------------------------------------------------
__global__ void __launch_bounds__(NCC)
k_cc_final(const int* __restrict__ parent_g, const int* __restrict__ deg,
           const uint32_t* __restrict__ surv, const int* __restrict__ scnt,
           const int* __restrict__ mcnt, const uint32_t* __restrict__ mbuf,
           int* __restrict__ rm, uint32_t* __restrict__ bufA, uint32_t* __restrict__ bufB,
           int* __restrict__ rank, float* __restrict__ out) {
    __shared__ int parent[N_PTS];                    // 64 KB
    __shared__ int s_nout;
    __shared__ int wsum[16];
    const int tid = threadIdx.x;
    const int lane = tid & 63;
    const uint64_t lane_lt = (1ull << lane) - 1;

#pragma unroll
    for (int k = 0; k < CHUNK; ++k) {
        int x = k * NCC + tid;
        parent[x] = parent_g[x];
    }
    __syncthreads();

    // initial compress (replaces the old 2nd k_jump): wavefront chase
    {
        int v[CHUNK];
#pragma unroll
        for (int k = 0; k < CHUNK; ++k) v[k] = parent[k * NCC + tid];
        bool any = true;
        while (any) {
            any = false;
#pragma unroll
            for (int k = 0; k < CHUNK; ++k) {
                int q = parent[v[k]];
                if (q != v[k]) { v[k] = q; any = true; }
            }
        }
#pragma unroll
        for (int k = 0; k < CHUNK; ++k) parent[k * NCC + tid] = v[k];
    }
    __syncthreads();

    int n_in = min(pload(scnt), SCAP);
    const uint32_t* cur = surv;

    // contraction rounds over the (small) survivor list
    for (int r = 0; r < 24; ++r) {
        uint32_t* nxt = (r & 1) ? bufB : bufA;
        if (tid == 0) s_nout = 0;
        __syncthreads();
        const int n4 = (n_in + 3) & ~3;
        for (int bb = tid * 4; bb < n4; bb += NCC * 4) {
            uint4 pk = *(const uint4*)(cur + bb);
#pragma unroll
            for (int k = 0; k < 4; ++k) {
                uint32_t p = (k == 0) ? pk.x : (k == 1) ? pk.y : (k == 2) ? pk.z : pk.w;
                bool valid = (bb + k) < n_in;
                int ri = 0, rj = 0;
                if (valid) {
                    ri = parent[(int)(p >> 14)];
                    rj = parent[(int)(p & (N_PTS - 1))];
                }
                bool live = valid && (ri != rj);
                int lo = min(ri, rj), hi = max(ri, rj);
                if (live) atomicMin(&parent[hi], lo);     // LDS fire-and-forget
                uint64_t m = __ballot(live);
                if (m) {
                    int ldr = (int)__ffsll((unsigned long long)m) - 1;
                    int base = 0;
                    if (lane == ldr) base = atomicAdd(&s_nout, (int)__popcll(m));
                    base = __shfl(base, ldr);
                    if (live) {
                        int pos = base + (int)__popcll(m & lane_lt);
                        if (pos < SCAP) nxt[pos] = ((uint32_t)hi << 14) | (uint32_t)lo;
                    }
                }
            }
        }
        __syncthreads();
        // compress: wavefront chase, 16 independent streams per thread
        int v[CHUNK];
#pragma unroll
        for (int k = 0; k < CHUNK; ++k) v[k] = parent[k * NCC + tid];
        bool any = true;
        while (any) {
            any = false;
#pragma unroll
            for (int k = 0; k < CHUNK; ++k) {
                int q = parent[v[k]];
                if (q != v[k]) { v[k] = q; any = true; }
            }
        }
#pragma unroll
        for (int k = 0; k < CHUNK; ++k) parent[k * NCC + tid] = v[k];
        __syncthreads();
        int nout = s_nout;
        if (nout == 0) break;                        // uniform
        n_in = min(nout, SCAP);
        cur = nxt;
    }

    // border root-min over mixed edges (global fire-and-forget)
    int nm = min(pload(mcnt), MCAP);
    for (int e = tid; e < nm; e += NCC) {
        uint32_t p = mbuf[e];
        int c = (int)(p >> 14), b = (int)(p & (N_PTS - 1));
        atomicMin(&rm[b], parent[c]);                // parent[c] = final root
    }

    // rank = exclusive count of core roots before each root index
    const int base_node = tid * CHUNK;
    int fl[CHUNK];
    int s = 0;
#pragma unroll
    for (int k = 0; k < CHUNK; ++k) {
        int x = base_node + k;
        fl[k] = (parent[x] == x && deg[x] >= MINPTS) ? 1 : 0;
        s += fl[k];
    }
    int wv = tid >> 6;                               // 16 waves
    int incl = s;
#pragma unroll
    for (int d = 1; d < 64; d <<= 1) {
        int t = __shfl_up(incl, d, 64);
        if (lane >= d) incl += t;
    }
    if (lane == 63) wsum[wv] = incl;
    __syncthreads();
    int wbase = 0;
    for (int w = 0; w < wv; ++w) wbase += wsum[w];
    int c = wbase + incl - s;
#pragma unroll
    for (int k = 0; k < CHUNK; ++k)
        if (fl[k]) rank[base_node + k] = c++;
    __syncthreads();

    // labels
#pragma unroll
    for (int k = 0; k < CHUNK; ++k) {
        int x = k * NCC + tid;                       // coalesced
        if (deg[x] >= MINPTS) {
            out[x] = (float)rank[parent[x]];
        } else {
            int rv = pload(&rm[x]);
            out[x] = (rv < BIG) ? (float)rank[rv] : -1.0f;
        }
    }
}

extern "C" void kernel_launch(void* const* d_in, const int* in_sizes, int n_in,
                              void* d_out, int out_size, void* d_ws, size_t ws_size,
                              hipStream_t stream) {
    (void)in_sizes; (void)n_in; (void)out_size; (void)ws_size;
    const float* pts = (const float*)d_in[0];
    float* out = (float*)d_out;

    int* ibase = (int*)d_ws;
    int*      deg    = ibase + 0 * N_PTS;            // N
    int*      rm     = ibase + 1 * N_PTS;            // N
    int*      parent = ibase + 2 * N_PTS;            // N
    int*      rank   = ibase + 3 * N_PTS;            // N
    int*      cnts   = ibase + 4 * N_PTS;            // 64 words
    int*      gcnt = cnts + 0, *ccnt = cnts + 1, *mcnt = cnts + 2, *scnt = cnts + 3;
    uint32_t* edges  = (uint32_t*)(ibase + 4 * N_PTS + 64);
    uint32_t* cclist = edges  + ECAP + 16;
    uint32_t* mbuf   = cclist + CCAP + 16;
    uint32_t* surv   = mbuf   + MCAP + 16;
    uint32_t* bufA   = surv   + SCAP + 16;
    uint32_t* bufB   = bufA   + SCAP + 16;

    dim3 blk(BLOCK);
    dim3 gN(N_PTS / BLOCK);                          // 64
    k_init <<<gN, blk, 0, stream>>>(deg, rm, parent, cnts);
    k_edges<<<dim3(NBLK), blk, 0, stream>>>(pts, edges, gcnt, deg);
    k_hook0<<<dim3(256), blk, 0, stream>>>(edges, gcnt, deg, parent, cclist, ccnt, mbuf, mcnt);
    k_jump <<<gN, blk, 0, stream>>>(parent);
    k_hook1<<<dim3(256), blk, 0, stream>>>(cclist, ccnt, parent, surv, scnt);
    k_cc_final<<<dim3(1), dim3(NCC), 0, stream>>>(parent, deg, surv, scnt, mcnt, mbuf,
                                                  rm, bufA, bufB, rank, out);
}